// Round 2
// 1111.598 us; speedup vs baseline: 1.2103x; 1.2103x over previous
//
#include <hip/hip_runtime.h>
#include <hip/hip_bf16.h>
#include <math.h>

#define HD 1024   // hidden
#define FD 4096   // ffn
#define NE 8      // experts
#define CAP 4096  // per-expert bucket capacity

typedef __attribute__((ext_vector_type(8))) short short8;
typedef __attribute__((ext_vector_type(4))) float f32x4;

__device__ inline unsigned short f2b(float f) {
    union { float f; unsigned u; } v; v.f = f;
    unsigned r = v.u + 0x7FFF + ((v.u >> 16) & 1);   // round-to-nearest-even
    return (unsigned short)(r >> 16);
}

__device__ inline void gll16(const void* g, void* l) {
    __builtin_amdgcn_global_load_lds(
        (const __attribute__((address_space(1))) unsigned int*)g,
        (__attribute__((address_space(3))) unsigned int*)l, 16, 0, 0);
}

// ---------------- x fp32 -> bf16 ----------------
__global__ __launch_bounds__(256) void convx_kernel(const float* __restrict__ x,
                                                    unsigned short* __restrict__ xbf)
{
    int i = blockIdx.x * 256 + threadIdx.x;   // each handles 4 elements
    float4 v = *(const float4*)(x + (size_t)i * 4);
    ushort4 b; b.x = f2b(v.x); b.y = f2b(v.y); b.z = f2b(v.z); b.w = f2b(v.w);
    *(ushort4*)(xbf + (size_t)i * 4) = b;
}

// ---------------- transpose+convert: in [R][C] fp32 -> out [C][R] bf16, linear ----------------
__global__ __launch_bounds__(256) void transpose_kernel(const float* __restrict__ in,
                                                        unsigned short* __restrict__ out,
                                                        int R, int C)
{
    __shared__ unsigned short Ls[64 * 72];
    int t = threadIdx.x;
    int r0 = blockIdx.x * 64, c0 = blockIdx.y * 64;
    const float* ip = in + (size_t)blockIdx.z * R * C;
    unsigned short* op = out + (size_t)blockIdx.z * R * C;

    int rl = t >> 4, c4 = (t & 15) * 4;
#pragma unroll
    for (int p = 0; p < 4; p++) {
        int r = p * 16 + rl;
        float4 v = *(const float4*)(ip + (size_t)(r0 + r) * C + c0 + c4);
        Ls[(c4 + 0) * 72 + r] = f2b(v.x);
        Ls[(c4 + 1) * 72 + r] = f2b(v.y);
        Ls[(c4 + 2) * 72 + r] = f2b(v.z);
        Ls[(c4 + 3) * 72 + r] = f2b(v.w);
    }
    __syncthreads();
    int c = t >> 2, j2 = (t & 3) * 2;
#pragma unroll
    for (int q = 0; q < 2; q++) {
        int j = j2 + q;
        uint4 v = *(const uint4*)&Ls[c * 72 + j * 8];
        *(uint4*)(op + (size_t)(c0 + c) * R + r0 + j * 8) = v;
    }
}

// ---------------- gating: one wave per token ----------------
__global__ __launch_bounds__(256) void gate_kernel(
    const float* __restrict__ x, const float* __restrict__ Wg,
    const float* __restrict__ bg, int* __restrict__ cnt,
    int* __restrict__ btok, float* __restrict__ bw,
    int* __restrict__ tokSlot, int T)
{
    int wave = threadIdx.x >> 6;
    int lane = threadIdx.x & 63;
    int t = blockIdx.x * 4 + wave;
    if (t >= T) return;

    float part[NE];
#pragma unroll
    for (int e = 0; e < NE; e++) part[e] = 0.f;
    const float* xr = x + (size_t)t * HD;
#pragma unroll 4
    for (int j = 0; j < 16; j++) {
        int h = lane + 64 * j;
        float xv = xr[h];
        const float* wr = Wg + h * NE;
#pragma unroll
        for (int e = 0; e < NE; e++) part[e] += xv * wr[e];
    }
#pragma unroll
    for (int e = 0; e < NE; e++) {
        float v = part[e];
        for (int off = 32; off >= 1; off >>= 1) v += __shfl_xor(v, off, 64);
        part[e] = v;
    }
    if (lane == 0) {
        float lg[NE];
#pragma unroll
        for (int e = 0; e < NE; e++) lg[e] = part[e] + bg[e];
        int i0 = 0;
        for (int e = 1; e < NE; e++) if (lg[e] > lg[i0]) i0 = e;
        int i1 = -1;
        for (int e = 0; e < NE; e++) {
            if (e == i0) continue;
            if (i1 < 0 || lg[e] > lg[i1]) i1 = e;
        }
        float e1 = expf(lg[i1] - lg[i0]);
        float s = 1.0f + e1;
        float w0 = 1.0f / s, w1 = e1 / s;
        int p0 = atomicAdd(&cnt[i0], 1);
        int p1 = atomicAdd(&cnt[i1], 1);
        btok[i0 * CAP + p0] = t; bw[i0 * CAP + p0] = w0;
        btok[i1 * CAP + p1] = t; bw[i1 * CAP + p1] = w1;
        tokSlot[t * 2 + 0] = i0 * CAP + p0;
        tokSlot[t * 2 + 1] = i1 * CAP + p1;
    }
}

__global__ void scan_kernel(const int* __restrict__ cnt, int* __restrict__ offs)
{
    if (threadIdx.x == 0) {
        int acc = 0;
        for (int e = 0; e < NE; e++) { offs[e] = acc; acc += cnt[e]; }
    }
}

// ---------------- GEMM1: h = silu(x@W1) * (x@W3) ----------------
// 128 tokens x 128 F, BK=32, double-buffered LDS.
// LDS layout per matrix/buffer: chunk-major [4 kchunks][128 rows][8 shorts]
//  -> ds_read_b128 fragment reads are bank-conflict-free (16-lane groups walk
//     16 consecutive 16B slots = each granule-slot exactly 2x = free).
// Staging: wave w owns k-chunk w; each gll16 fills one contiguous 1KB region
// (64 rows x 16B), per-lane GLOBAL address carries the row mapping.
// grid: (x = f-block, y = m-block, z = expert): blocks sharing a weight panel
// differ by id multiples of 32 -> same XCD -> weight re-reads served by L2.
__global__ __launch_bounds__(256, 2) void gemm1_kernel(
    const unsigned short* __restrict__ xbf, const unsigned short* __restrict__ Wt1,
    const unsigned short* __restrict__ Wt3, const int* __restrict__ btok,
    const int* __restrict__ cnt, const int* __restrict__ offs,
    unsigned short* __restrict__ h_buf)
{
    int e = blockIdx.z;
    int ne = cnt[e];
    int m0 = blockIdx.y * 128;
    if (m0 >= ne) return;
    int f0 = blockIdx.x * 128;

    __shared__ unsigned short As[2][4096];
    __shared__ unsigned short B1s[2][4096];
    __shared__ unsigned short B3s[2][4096];

    int tid = threadIdx.x;
    int lane = tid & 63;
    int w = tid >> 6;
    int wm = (w >> 1) * 64, wn = (w & 1) * 64;
    int l15 = lane & 15, quad = lane >> 4;

    const unsigned short* W1e = Wt1 + (size_t)e * HD * FD;
    const unsigned short* W3e = Wt3 + (size_t)e * HD * FD;

    // staging: wave w = k-chunk w; q = row-half. dst is wave-uniform.
    const unsigned short* aA[2];
    const unsigned short* aB1[2];
    const unsigned short* aB3[2];
    int dst[2];
#pragma unroll
    for (int q = 0; q < 2; q++) {
        int row = q * 64 + lane;             // 0..127 (per-lane global row)
        dst[q] = w * 1024 + q * 512;         // shorts; lane l lands at +l*8
        int ridx = m0 + row; if (ridx >= ne) ridx = ne - 1;
        int tok = btok[e * CAP + ridx];
        aA[q]  = xbf + (size_t)tok * HD + w * 8;
        aB1[q] = W1e + (size_t)(f0 + row) * HD + w * 8;
        aB3[q] = W3e + (size_t)(f0 + row) * HD + w * 8;
    }

    // fragment read offsets (shorts): chunk-major addr = quad*1024 + row*8
    int aoff[4], boff[4];
#pragma unroll
    for (int i = 0; i < 4; i++) {
        aoff[i] = quad * 1024 + (wm + i * 16 + l15) * 8;
        boff[i] = quad * 1024 + (wn + i * 16 + l15) * 8;
    }

    f32x4 accG[4][4], accU[4][4];
    f32x4 z = {0.f, 0.f, 0.f, 0.f};
#pragma unroll
    for (int i = 0; i < 4; i++)
#pragma unroll
        for (int jj = 0; jj < 4; jj++) { accG[i][jj] = z; accU[i][jj] = z; }

    // prologue: stage k=0 into buf 0
#pragma unroll
    for (int q = 0; q < 2; q++) {
        gll16(aA[q],  &As[0][dst[q]]);
        gll16(aB1[q], &B1s[0][dst[q]]);
        gll16(aB3[q], &B3s[0][dst[q]]);
    }
    __syncthreads();

    const int NK = HD / 32;   // 32
    int cur = 0;
#pragma unroll 2
    for (int k = 1; k <= NK; ++k) {
        // issue next-tile staging FIRST: latency hides under the MFMA phase,
        // the __syncthreads (vmcnt(0)+barrier) at the end lands it for next iter
        if (k < NK) {
            int k0 = k * 32;
#pragma unroll
            for (int q = 0; q < 2; q++) {
                gll16(aA[q]  + k0, &As[cur ^ 1][dst[q]]);
                gll16(aB1[q] + k0, &B1s[cur ^ 1][dst[q]]);
                gll16(aB3[q] + k0, &B3s[cur ^ 1][dst[q]]);
            }
        }
        short8 af[4], b1f[4], b3f[4];
#pragma unroll
        for (int mt = 0; mt < 4; mt++) af[mt] = *(const short8*)&As[cur][aoff[mt]];
#pragma unroll
        for (int nt = 0; nt < 4; nt++) {
            b1f[nt] = *(const short8*)&B1s[cur][boff[nt]];
            b3f[nt] = *(const short8*)&B3s[cur][boff[nt]];
        }
#pragma unroll
        for (int mt = 0; mt < 4; mt++)
#pragma unroll
            for (int nt = 0; nt < 4; nt++) {
                accG[mt][nt] = __builtin_amdgcn_mfma_f32_16x16x32_bf16(af[mt], b1f[nt], accG[mt][nt], 0, 0, 0);
                accU[mt][nt] = __builtin_amdgcn_mfma_f32_16x16x32_bf16(af[mt], b3f[nt], accU[mt][nt], 0, 0, 0);
            }
        __syncthreads();
        cur ^= 1;
    }

    // epilogue: silu(g)*u -> bf16 -> h_buf (linear layout)
    int base = offs[e] + m0;
#pragma unroll
    for (int mt = 0; mt < 4; mt++) {
#pragma unroll
        for (int r = 0; r < 4; r++) {
            int rowl = wm + mt * 16 + quad * 4 + r;
            if (m0 + rowl < ne) {
                size_t rb = (size_t)(base + rowl) * FD;
#pragma unroll
                for (int nt = 0; nt < 4; nt++) {
                    int f = f0 + wn + nt * 16 + l15;
                    float g = accG[mt][nt][r];
                    float u = accU[mt][nt][r];
                    float h = g / (1.f + expf(-g)) * u;
                    h_buf[rb + f] = f2b(h);
                }
            }
        }
    }
}

// ---------------- GEMM2: contrib = cw * (h @ W2) ----------------
// BK=32, double-buffered, chunk-major LDS, 3 blocks/CU.
// grid: (x = h-block, y = m-block, z = expert) -> same-x blocks on same XCD.
__global__ __launch_bounds__(256, 3) void gemm2_kernel(
    const unsigned short* __restrict__ h_buf, const unsigned short* __restrict__ Wt2,
    const float* __restrict__ bw, const int* __restrict__ cnt,
    const int* __restrict__ offs, float* __restrict__ contrib)
{
    int e = blockIdx.z;
    int ne = cnt[e];
    int m0 = blockIdx.y * 128;
    if (m0 >= ne) return;
    int h0 = blockIdx.x * 128;

    __shared__ unsigned short As[2][4096];
    __shared__ unsigned short Bs[2][4096];

    int tid = threadIdx.x;
    int lane = tid & 63;
    int w = tid >> 6;
    int wm = (w >> 1) * 64, wn = (w & 1) * 64;
    int l15 = lane & 15, quad = lane >> 4;
    int obase = offs[e];

    const unsigned short* W2e = Wt2 + (size_t)e * FD * HD;

    const unsigned short* aA[2];
    const unsigned short* aB[2];
    int dst[2];
#pragma unroll
    for (int q = 0; q < 2; q++) {
        int row = q * 64 + lane;
        dst[q] = w * 1024 + q * 512;
        int ridx = m0 + row; if (ridx >= ne) ridx = ne - 1;
        aA[q] = h_buf + (size_t)(obase + ridx) * FD + w * 8;
        aB[q] = W2e + (size_t)(h0 + row) * FD + w * 8;
    }

    int aoff[4], boff[4];
#pragma unroll
    for (int i = 0; i < 4; i++) {
        aoff[i] = quad * 1024 + (wm + i * 16 + l15) * 8;
        boff[i] = quad * 1024 + (wn + i * 16 + l15) * 8;
    }

    f32x4 acc[4][4];
    f32x4 z = {0.f, 0.f, 0.f, 0.f};
#pragma unroll
    for (int i = 0; i < 4; i++)
#pragma unroll
        for (int jj = 0; jj < 4; jj++) acc[i][jj] = z;

#pragma unroll
    for (int q = 0; q < 2; q++) {
        gll16(aA[q], &As[0][dst[q]]);
        gll16(aB[q], &Bs[0][dst[q]]);
    }
    __syncthreads();

    const int NK = FD / 32;   // 128
    int cur = 0;
#pragma unroll 2
    for (int k = 1; k <= NK; ++k) {
        if (k < NK) {
            int k0 = k * 32;
#pragma unroll
            for (int q = 0; q < 2; q++) {
                gll16(aA[q] + k0, &As[cur ^ 1][dst[q]]);
                gll16(aB[q] + k0, &Bs[cur ^ 1][dst[q]]);
            }
        }
        short8 af[4], bf[4];
#pragma unroll
        for (int mt = 0; mt < 4; mt++) af[mt] = *(const short8*)&As[cur][aoff[mt]];
#pragma unroll
        for (int nt = 0; nt < 4; nt++) bf[nt] = *(const short8*)&Bs[cur][boff[nt]];
#pragma unroll
        for (int mt = 0; mt < 4; mt++)
#pragma unroll
            for (int nt = 0; nt < 4; nt++)
                acc[mt][nt] = __builtin_amdgcn_mfma_f32_16x16x32_bf16(af[mt], bf[nt], acc[mt][nt], 0, 0, 0);
        __syncthreads();
        cur ^= 1;
    }

    int base = obase + m0;
#pragma unroll
    for (int mt = 0; mt < 4; mt++) {
#pragma unroll
        for (int r = 0; r < 4; r++) {
            int rowl = wm + mt * 16 + quad * 4 + r;
            if (m0 + rowl < ne) {
                float wgt = bw[e * CAP + m0 + rowl];
                size_t rb = (size_t)(base + rowl) * HD;
#pragma unroll
                for (int nt = 0; nt < 4; nt++) {
                    int col = h0 + wn + nt * 16 + l15;
                    contrib[rb + col] = acc[mt][nt][r] * wgt;
                }
            }
        }
    }
}

// ---------------- combine ----------------
__global__ __launch_bounds__(256) void combine_kernel(
    const float* __restrict__ contrib, const int* __restrict__ tokSlot,
    const int* __restrict__ offs, float* __restrict__ out)
{
    int t = blockIdx.x;
    int i = threadIdx.x;
    int s0 = tokSlot[t * 2 + 0];
    int s1 = tokSlot[t * 2 + 1];
    int r0 = offs[s0 >> 12] + (s0 & (CAP - 1));
    int r1 = offs[s1 >> 12] + (s1 & (CAP - 1));
    float4 a = *(const float4*)(contrib + (size_t)r0 * HD + i * 4);
    float4 b = *(const float4*)(contrib + (size_t)r1 * HD + i * 4);
    float4 o;
    o.x = a.x + b.x; o.y = a.y + b.y; o.z = a.z + b.z; o.w = a.w + b.w;
    *(float4*)(out + (size_t)t * HD + i * 4) = o;
}

extern "C" void kernel_launch(void* const* d_in, const int* in_sizes, int n_in,
                              void* d_out, int out_size, void* d_ws, size_t ws_size,
                              hipStream_t stream)
{
    const float* x  = (const float*)d_in[0];
    const float* Wg = (const float*)d_in[1];
    const float* bg = (const float*)d_in[2];
    const float* W1 = (const float*)d_in[3];
    const float* W3 = (const float*)d_in[4];
    const float* W2 = (const float*)d_in[5];
    float* out = (float*)d_out;
    int T = in_sizes[0] / HD;   // 4096 tokens

    // ws layout (~304 MB)
    char* ws = (char*)d_ws;
    int*   cnt     = (int*)ws;
    int*   offs    = cnt + 8;
    int*   btok    = (int*)(ws + 1024);
    float* bw      = (float*)(ws + 1024 + 131072);
    int*   tokSlot = (int*)(ws + 1024 + 262144);
    unsigned short* xbf = (unsigned short*)(ws + ((size_t)1 << 20));                 // 8 MB
    unsigned short* Wt1 = (unsigned short*)(ws + ((size_t)16 << 20));                // 64 MB
    unsigned short* Wt3 = (unsigned short*)(ws + ((size_t)80 << 20));                // 64 MB
    unsigned short* Wt2 = (unsigned short*)(ws + ((size_t)144 << 20));               // 64 MB
    unsigned short* h_buf = (unsigned short*)(ws + ((size_t)208 << 20));             // 64 MB
    float* contrib = (float*)(ws + ((size_t)272 << 20));                             // 32 MB

    hipMemsetAsync(cnt, 0, 8 * sizeof(int), stream);

    convx_kernel<<<(T * HD) / 1024, 256, 0, stream>>>(x, xbf);
    dim3 tg1(HD / 64, FD / 64, NE);
    transpose_kernel<<<tg1, 256, 0, stream>>>(W1, Wt1, HD, FD);
    transpose_kernel<<<tg1, 256, 0, stream>>>(W3, Wt3, HD, FD);
    dim3 tg2(FD / 64, HD / 64, NE);
    transpose_kernel<<<tg2, 256, 0, stream>>>(W2, Wt2, FD, HD);

    gate_kernel<<<(T + 3) / 4, 256, 0, stream>>>(x, Wg, bg, cnt, btok, bw, tokSlot, T);
    scan_kernel<<<1, 64, 0, stream>>>(cnt, offs);

    dim3 g1(FD / 128, CAP / 128, NE);
    gemm1_kernel<<<g1, 256, 0, stream>>>(xbf, Wt1, Wt3, btok, cnt, offs, h_buf);

    dim3 g2(HD / 128, CAP / 128, NE);
    gemm2_kernel<<<g2, 256, 0, stream>>>(h_buf, Wt2, bw, cnt, offs, contrib);

    combine_kernel<<<T, 256, 0, stream>>>(contrib, tokSlot, offs, out);
}

// Round 3
// 1011.841 us; speedup vs baseline: 1.3296x; 1.0986x over previous
//
#include <hip/hip_runtime.h>
#include <hip/hip_bf16.h>
#include <math.h>

#define HD 1024   // hidden
#define FD 4096   // ffn
#define NE 8      // experts
#define CAP 4096  // per-expert bucket capacity

typedef __attribute__((ext_vector_type(8))) short short8;
typedef __attribute__((ext_vector_type(4))) float f32x4;

__device__ inline unsigned short f2b(float f) {
    union { float f; unsigned u; } v; v.f = f;
    unsigned r = v.u + 0x7FFF + ((v.u >> 16) & 1);   // round-to-nearest-even
    return (unsigned short)(r >> 16);
}

__device__ inline void gll16(const void* g, void* l) {
    __builtin_amdgcn_global_load_lds(
        (const __attribute__((address_space(1))) unsigned int*)g,
        (__attribute__((address_space(3))) unsigned int*)l, 16, 0, 0);
}

// ---------------- x fp32 -> bf16 ----------------
__global__ __launch_bounds__(256) void convx_kernel(const float* __restrict__ x,
                                                    unsigned short* __restrict__ xbf)
{
    int i = blockIdx.x * 256 + threadIdx.x;   // each handles 4 elements
    float4 v = *(const float4*)(x + (size_t)i * 4);
    ushort4 b; b.x = f2b(v.x); b.y = f2b(v.y); b.z = f2b(v.z); b.w = f2b(v.w);
    *(ushort4*)(xbf + (size_t)i * 4) = b;
}

// ---------------- transpose+convert: in [R][C] fp32 -> out [C][R] bf16, linear ----------------
__global__ __launch_bounds__(256) void transpose_kernel(const float* __restrict__ in,
                                                        unsigned short* __restrict__ out,
                                                        int R, int C)
{
    __shared__ unsigned short Ls[64 * 72];
    int t = threadIdx.x;
    int r0 = blockIdx.x * 64, c0 = blockIdx.y * 64;
    const float* ip = in + (size_t)blockIdx.z * R * C;
    unsigned short* op = out + (size_t)blockIdx.z * R * C;

    int rl = t >> 4, c4 = (t & 15) * 4;
#pragma unroll
    for (int p = 0; p < 4; p++) {
        int r = p * 16 + rl;
        float4 v = *(const float4*)(ip + (size_t)(r0 + r) * C + c0 + c4);
        Ls[(c4 + 0) * 72 + r] = f2b(v.x);
        Ls[(c4 + 1) * 72 + r] = f2b(v.y);
        Ls[(c4 + 2) * 72 + r] = f2b(v.z);
        Ls[(c4 + 3) * 72 + r] = f2b(v.w);
    }
    __syncthreads();
    int c = t >> 2, j2 = (t & 3) * 2;
#pragma unroll
    for (int q = 0; q < 2; q++) {
        int j = j2 + q;
        uint4 v = *(const uint4*)&Ls[c * 72 + j * 8];
        *(uint4*)(op + (size_t)(c0 + c) * R + r0 + j * 8) = v;
    }
}

// ---------------- gating: one wave per token ----------------
__global__ __launch_bounds__(256) void gate_kernel(
    const float* __restrict__ x, const float* __restrict__ Wg,
    const float* __restrict__ bg, int* __restrict__ cnt,
    int* __restrict__ btok, float* __restrict__ bw,
    int* __restrict__ tokSlot, int T)
{
    int wave = threadIdx.x >> 6;
    int lane = threadIdx.x & 63;
    int t = blockIdx.x * 4 + wave;
    if (t >= T) return;

    float part[NE];
#pragma unroll
    for (int e = 0; e < NE; e++) part[e] = 0.f;
    const float* xr = x + (size_t)t * HD;
#pragma unroll 4
    for (int j = 0; j < 16; j++) {
        int h = lane + 64 * j;
        float xv = xr[h];
        const float* wr = Wg + h * NE;
#pragma unroll
        for (int e = 0; e < NE; e++) part[e] += xv * wr[e];
    }
#pragma unroll
    for (int e = 0; e < NE; e++) {
        float v = part[e];
        for (int off = 32; off >= 1; off >>= 1) v += __shfl_xor(v, off, 64);
        part[e] = v;
    }
    if (lane == 0) {
        float lg[NE];
#pragma unroll
        for (int e = 0; e < NE; e++) lg[e] = part[e] + bg[e];
        int i0 = 0;
        for (int e = 1; e < NE; e++) if (lg[e] > lg[i0]) i0 = e;
        int i1 = -1;
        for (int e = 0; e < NE; e++) {
            if (e == i0) continue;
            if (i1 < 0 || lg[e] > lg[i1]) i1 = e;
        }
        float e1 = expf(lg[i1] - lg[i0]);
        float s = 1.0f + e1;
        float w0 = 1.0f / s, w1 = e1 / s;
        int p0 = atomicAdd(&cnt[i0], 1);
        int p1 = atomicAdd(&cnt[i1], 1);
        btok[i0 * CAP + p0] = t; bw[i0 * CAP + p0] = w0;
        btok[i1 * CAP + p1] = t; bw[i1 * CAP + p1] = w1;
        tokSlot[t * 2 + 0] = i0 * CAP + p0;
        tokSlot[t * 2 + 1] = i1 * CAP + p1;
    }
}

__global__ void scan_kernel(const int* __restrict__ cnt, int* __restrict__ offs)
{
    if (threadIdx.x == 0) {
        int acc = 0;
        for (int e = 0; e < NE; e++) { offs[e] = acc; acc += cnt[e]; }
    }
}

// ---------------- GEMM1: h = silu(x@W1) * (x@W3) ----------------
// 128 tokens x 128 F, BK=32, 3-deep LDS pipeline (prefetch distance 2) with
// counted s_waitcnt vmcnt(12) — stage loads for k+1,k+2 stay in flight across
// the barrier (T3+T4). Chunk-major LDS [4 kchunks][128 rows][8 shorts] keeps
// ds_read_b128 fragment reads conflict-free with wave-uniform gll16 dests.
// grid: (x = f-block, y = m-block, z = expert): blocks sharing a weight panel
// land on the same XCD -> weight re-reads served by L2.
__global__ __launch_bounds__(256, 2) void gemm1_kernel(
    const unsigned short* __restrict__ xbf, const unsigned short* __restrict__ Wt1,
    const unsigned short* __restrict__ Wt3, const int* __restrict__ btok,
    const int* __restrict__ cnt, const int* __restrict__ offs,
    unsigned short* __restrict__ h_buf)
{
    int e = blockIdx.z;
    int ne = cnt[e];
    int m0 = blockIdx.y * 128;
    if (m0 >= ne) return;
    int f0 = blockIdx.x * 128;

    __shared__ unsigned short As[3][4096];
    __shared__ unsigned short B1s[3][4096];
    __shared__ unsigned short B3s[3][4096];

    int tid = threadIdx.x;
    int lane = tid & 63;
    int w = tid >> 6;
    int wm = (w >> 1) * 64, wn = (w & 1) * 64;
    int l15 = lane & 15, quad = lane >> 4;

    const unsigned short* W1e = Wt1 + (size_t)e * HD * FD;
    const unsigned short* W3e = Wt3 + (size_t)e * HD * FD;

    // staging: wave w = k-chunk w; q = row-half. dst is wave-uniform.
    const unsigned short* aA[2];
    const unsigned short* aB1[2];
    const unsigned short* aB3[2];
    int dst[2];
#pragma unroll
    for (int q = 0; q < 2; q++) {
        int row = q * 64 + lane;             // 0..127 (per-lane global row)
        dst[q] = w * 1024 + q * 512;         // shorts; lane l lands at +l*8
        int ridx = m0 + row; if (ridx >= ne) ridx = ne - 1;
        int tok = btok[e * CAP + ridx];
        aA[q]  = xbf + (size_t)tok * HD + w * 8;
        aB1[q] = W1e + (size_t)(f0 + row) * HD + w * 8;
        aB3[q] = W3e + (size_t)(f0 + row) * HD + w * 8;
    }

    // fragment read offsets (shorts): chunk-major addr = quad*1024 + row*8
    int aoff[4], boff[4];
#pragma unroll
    for (int i = 0; i < 4; i++) {
        aoff[i] = quad * 1024 + (wm + i * 16 + l15) * 8;
        boff[i] = quad * 1024 + (wn + i * 16 + l15) * 8;
    }

    f32x4 accG[4][4], accU[4][4];
    f32x4 z = {0.f, 0.f, 0.f, 0.f};
#pragma unroll
    for (int i = 0; i < 4; i++)
#pragma unroll
        for (int jj = 0; jj < 4; jj++) { accG[i][jj] = z; accU[i][jj] = z; }

    // prologue: stage k=0 -> buf0, k=1 -> buf1
#pragma unroll
    for (int q = 0; q < 2; q++) {
        gll16(aA[q],  &As[0][dst[q]]);
        gll16(aB1[q], &B1s[0][dst[q]]);
        gll16(aB3[q], &B3s[0][dst[q]]);
    }
#pragma unroll
    for (int q = 0; q < 2; q++) {
        gll16(aA[q]  + 32, &As[1][dst[q]]);
        gll16(aB1[q] + 32, &B1s[1][dst[q]]);
        gll16(aB3[q] + 32, &B3s[1][dst[q]]);
    }

    const int NK = HD / 32;   // 32
    int cur = 0;
    for (int k = 0; k < NK; ++k) {
        // stage k+2 into buf (cur+2)%3 (overwrites buffer last read at iter k-1;
        // the trailing barrier of iter k-1 makes that safe)
        if (k + 2 < NK) {
            int nb = cur + 2; if (nb >= 3) nb -= 3;
            int k0 = (k + 2) * 32;
#pragma unroll
            for (int q = 0; q < 2; q++) {
                gll16(aA[q]  + k0, &As[nb][dst[q]]);
                gll16(aB1[q] + k0, &B1s[nb][dst[q]]);
                gll16(aB3[q] + k0, &B3s[nb][dst[q]]);
            }
            // counted wait: keep the 12 loads of tiles k+1,k+2 in flight
            asm volatile("s_waitcnt vmcnt(12)\ns_barrier" ::: "memory");
        } else if (k + 1 < NK) {
            asm volatile("s_waitcnt vmcnt(6)\ns_barrier" ::: "memory");
        } else {
            asm volatile("s_waitcnt vmcnt(0)\ns_barrier" ::: "memory");
        }

        __builtin_amdgcn_s_setprio(1);
        short8 af[4], b1f[4], b3f[4];
#pragma unroll
        for (int mt = 0; mt < 4; mt++) af[mt] = *(const short8*)&As[cur][aoff[mt]];
#pragma unroll
        for (int nt = 0; nt < 4; nt++) {
            b1f[nt] = *(const short8*)&B1s[cur][boff[nt]];
            b3f[nt] = *(const short8*)&B3s[cur][boff[nt]];
        }
#pragma unroll
        for (int mt = 0; mt < 4; mt++)
#pragma unroll
            for (int nt = 0; nt < 4; nt++) {
                accG[mt][nt] = __builtin_amdgcn_mfma_f32_16x16x32_bf16(af[mt], b1f[nt], accG[mt][nt], 0, 0, 0);
                accU[mt][nt] = __builtin_amdgcn_mfma_f32_16x16x32_bf16(af[mt], b3f[nt], accU[mt][nt], 0, 0, 0);
            }
        __builtin_amdgcn_s_setprio(0);
        asm volatile("s_barrier" ::: "memory");
        cur++; if (cur >= 3) cur -= 3;
    }

    // epilogue: silu(g)*u -> bf16 -> h_buf (linear layout)
    int base = offs[e] + m0;
#pragma unroll
    for (int mt = 0; mt < 4; mt++) {
#pragma unroll
        for (int r = 0; r < 4; r++) {
            int rowl = wm + mt * 16 + quad * 4 + r;
            if (m0 + rowl < ne) {
                size_t rb = (size_t)(base + rowl) * FD;
#pragma unroll
                for (int nt = 0; nt < 4; nt++) {
                    int f = f0 + wn + nt * 16 + l15;
                    float g = accG[mt][nt][r];
                    float u = accU[mt][nt][r];
                    float h = g / (1.f + expf(-g)) * u;
                    h_buf[rb + f] = f2b(h);
                }
            }
        }
    }
}

// ---------------- GEMM2: contrib = cw * (h @ W2) ----------------
// BK=32, 3-deep pipeline with vmcnt(8), chunk-major LDS, 3 blocks/CU.
// grid: (x = h-block, y = m-block, z = expert) -> same-x blocks on same XCD.
__global__ __launch_bounds__(256, 3) void gemm2_kernel(
    const unsigned short* __restrict__ h_buf, const unsigned short* __restrict__ Wt2,
    const float* __restrict__ bw, const int* __restrict__ cnt,
    const int* __restrict__ offs, float* __restrict__ contrib)
{
    int e = blockIdx.z;
    int ne = cnt[e];
    int m0 = blockIdx.y * 128;
    if (m0 >= ne) return;
    int h0 = blockIdx.x * 128;

    __shared__ unsigned short As[3][4096];
    __shared__ unsigned short Bs[3][4096];

    int tid = threadIdx.x;
    int lane = tid & 63;
    int w = tid >> 6;
    int wm = (w >> 1) * 64, wn = (w & 1) * 64;
    int l15 = lane & 15, quad = lane >> 4;
    int obase = offs[e];

    const unsigned short* W2e = Wt2 + (size_t)e * FD * HD;

    const unsigned short* aA[2];
    const unsigned short* aB[2];
    int dst[2];
#pragma unroll
    for (int q = 0; q < 2; q++) {
        int row = q * 64 + lane;
        dst[q] = w * 1024 + q * 512;
        int ridx = m0 + row; if (ridx >= ne) ridx = ne - 1;
        aA[q] = h_buf + (size_t)(obase + ridx) * FD + w * 8;
        aB[q] = W2e + (size_t)(h0 + row) * FD + w * 8;
    }

    int aoff[4], boff[4];
#pragma unroll
    for (int i = 0; i < 4; i++) {
        aoff[i] = quad * 1024 + (wm + i * 16 + l15) * 8;
        boff[i] = quad * 1024 + (wn + i * 16 + l15) * 8;
    }

    f32x4 acc[4][4];
    f32x4 z = {0.f, 0.f, 0.f, 0.f};
#pragma unroll
    for (int i = 0; i < 4; i++)
#pragma unroll
        for (int jj = 0; jj < 4; jj++) acc[i][jj] = z;

#pragma unroll
    for (int q = 0; q < 2; q++) {
        gll16(aA[q], &As[0][dst[q]]);
        gll16(aB[q], &Bs[0][dst[q]]);
    }
#pragma unroll
    for (int q = 0; q < 2; q++) {
        gll16(aA[q] + 32, &As[1][dst[q]]);
        gll16(aB[q] + 32, &Bs[1][dst[q]]);
    }

    const int NK = FD / 32;   // 128
    int cur = 0;
    for (int k = 0; k < NK; ++k) {
        if (k + 2 < NK) {
            int nb = cur + 2; if (nb >= 3) nb -= 3;
            int k0 = (k + 2) * 32;
#pragma unroll
            for (int q = 0; q < 2; q++) {
                gll16(aA[q] + k0, &As[nb][dst[q]]);
                gll16(aB[q] + k0, &Bs[nb][dst[q]]);
            }
            asm volatile("s_waitcnt vmcnt(8)\ns_barrier" ::: "memory");
        } else if (k + 1 < NK) {
            asm volatile("s_waitcnt vmcnt(4)\ns_barrier" ::: "memory");
        } else {
            asm volatile("s_waitcnt vmcnt(0)\ns_barrier" ::: "memory");
        }

        __builtin_amdgcn_s_setprio(1);
        short8 af[4], bf[4];
#pragma unroll
        for (int mt = 0; mt < 4; mt++) af[mt] = *(const short8*)&As[cur][aoff[mt]];
#pragma unroll
        for (int nt = 0; nt < 4; nt++) bf[nt] = *(const short8*)&Bs[cur][boff[nt]];
#pragma unroll
        for (int mt = 0; mt < 4; mt++)
#pragma unroll
            for (int nt = 0; nt < 4; nt++)
                acc[mt][nt] = __builtin_amdgcn_mfma_f32_16x16x32_bf16(af[mt], bf[nt], acc[mt][nt], 0, 0, 0);
        __builtin_amdgcn_s_setprio(0);
        asm volatile("s_barrier" ::: "memory");
        cur++; if (cur >= 3) cur -= 3;
    }

    int base = obase + m0;
#pragma unroll
    for (int mt = 0; mt < 4; mt++) {
#pragma unroll
        for (int r = 0; r < 4; r++) {
            int rowl = wm + mt * 16 + quad * 4 + r;
            if (m0 + rowl < ne) {
                float wgt = bw[e * CAP + m0 + rowl];
                size_t rb = (size_t)(base + rowl) * HD;
#pragma unroll
                for (int nt = 0; nt < 4; nt++) {
                    int col = h0 + wn + nt * 16 + l15;
                    contrib[rb + col] = acc[mt][nt][r] * wgt;
                }
            }
        }
    }
}

// ---------------- combine ----------------
__global__ __launch_bounds__(256) void combine_kernel(
    const float* __restrict__ contrib, const int* __restrict__ tokSlot,
    const int* __restrict__ offs, float* __restrict__ out)
{
    int t = blockIdx.x;
    int i = threadIdx.x;
    int s0 = tokSlot[t * 2 + 0];
    int s1 = tokSlot[t * 2 + 1];
    int r0 = offs[s0 >> 12] + (s0 & (CAP - 1));
    int r1 = offs[s1 >> 12] + (s1 & (CAP - 1));
    float4 a = *(const float4*)(contrib + (size_t)r0 * HD + i * 4);
    float4 b = *(const float4*)(contrib + (size_t)r1 * HD + i * 4);
    float4 o;
    o.x = a.x + b.x; o.y = a.y + b.y; o.z = a.z + b.z; o.w = a.w + b.w;
    *(float4*)(out + (size_t)t * HD + i * 4) = o;
}

extern "C" void kernel_launch(void* const* d_in, const int* in_sizes, int n_in,
                              void* d_out, int out_size, void* d_ws, size_t ws_size,
                              hipStream_t stream)
{
    const float* x  = (const float*)d_in[0];
    const float* Wg = (const float*)d_in[1];
    const float* bg = (const float*)d_in[2];
    const float* W1 = (const float*)d_in[3];
    const float* W3 = (const float*)d_in[4];
    const float* W2 = (const float*)d_in[5];
    float* out = (float*)d_out;
    int T = in_sizes[0] / HD;   // 4096 tokens

    // ws layout (~304 MB)
    char* ws = (char*)d_ws;
    int*   cnt     = (int*)ws;
    int*   offs    = cnt + 8;
    int*   btok    = (int*)(ws + 1024);
    float* bw      = (float*)(ws + 1024 + 131072);
    int*   tokSlot = (int*)(ws + 1024 + 262144);
    unsigned short* xbf = (unsigned short*)(ws + ((size_t)1 << 20));                 // 8 MB
    unsigned short* Wt1 = (unsigned short*)(ws + ((size_t)16 << 20));                // 64 MB
    unsigned short* Wt3 = (unsigned short*)(ws + ((size_t)80 << 20));                // 64 MB
    unsigned short* Wt2 = (unsigned short*)(ws + ((size_t)144 << 20));               // 64 MB
    unsigned short* h_buf = (unsigned short*)(ws + ((size_t)208 << 20));             // 64 MB
    float* contrib = (float*)(ws + ((size_t)272 << 20));                             // 32 MB

    hipMemsetAsync(cnt, 0, 8 * sizeof(int), stream);

    convx_kernel<<<(T * HD) / 1024, 256, 0, stream>>>(x, xbf);
    dim3 tg1(HD / 64, FD / 64, NE);
    transpose_kernel<<<tg1, 256, 0, stream>>>(W1, Wt1, HD, FD);
    transpose_kernel<<<tg1, 256, 0, stream>>>(W3, Wt3, HD, FD);
    dim3 tg2(FD / 64, HD / 64, NE);
    transpose_kernel<<<tg2, 256, 0, stream>>>(W2, Wt2, FD, HD);

    gate_kernel<<<(T + 3) / 4, 256, 0, stream>>>(x, Wg, bg, cnt, btok, bw, tokSlot, T);
    scan_kernel<<<1, 64, 0, stream>>>(cnt, offs);

    dim3 g1(FD / 128, CAP / 128, NE);
    gemm1_kernel<<<g1, 256, 0, stream>>>(xbf, Wt1, Wt3, btok, cnt, offs, h_buf);

    dim3 g2(HD / 128, CAP / 128, NE);
    gemm2_kernel<<<g2, 256, 0, stream>>>(h_buf, Wt2, bw, cnt, offs, contrib);

    combine_kernel<<<T, 256, 0, stream>>>(contrib, tokSlot, offs, out);
}

// Round 5
// 865.892 us; speedup vs baseline: 1.5537x; 1.1686x over previous
//
#include <hip/hip_runtime.h>
#include <hip/hip_bf16.h>
#include <math.h>

#define HD 1024   // hidden
#define FD 4096   // ffn
#define NE 8      // experts
#define CAP 4096  // per-expert bucket capacity

typedef __attribute__((ext_vector_type(8))) short short8;
typedef __attribute__((ext_vector_type(4))) float f32x4;

__device__ inline unsigned short f2b(float f) {
    union { float f; unsigned u; } v; v.f = f;
    unsigned r = v.u + 0x7FFF + ((v.u >> 16) & 1);   // round-to-nearest-even
    return (unsigned short)(r >> 16);
}

__device__ inline void gll16(const void* g, void* l) {
    __builtin_amdgcn_global_load_lds(
        (const __attribute__((address_space(1))) unsigned int*)g,
        (__attribute__((address_space(3))) unsigned int*)l, 16, 0, 0);
}

// ---------------- x fp32 -> bf16 ----------------
__global__ __launch_bounds__(256) void convx_kernel(const float* __restrict__ x,
                                                    unsigned short* __restrict__ xbf)
{
    int i = blockIdx.x * 256 + threadIdx.x;   // each handles 4 elements
    float4 v = *(const float4*)(x + (size_t)i * 4);
    ushort4 b; b.x = f2b(v.x); b.y = f2b(v.y); b.z = f2b(v.z); b.w = f2b(v.w);
    *(ushort4*)(xbf + (size_t)i * 4) = b;
}

// ---------------- transpose+convert: in [R][C] fp32 -> out bf16, STAGING-PACKED ----------------
// output layout: [orow/128][ocol/32][orow%128][ocol%32]  (orow = input col, ocol = input row)
// -> each GEMM staging gll16 reads 1KB of CONTIGUOUS memory (8 full 128B lines).
__global__ __launch_bounds__(256) void transpose_kernel(const float* __restrict__ in,
                                                        unsigned short* __restrict__ out,
                                                        int R, int C)
{
    __shared__ unsigned short Ls[64 * 72];
    int t = threadIdx.x;
    int r0 = blockIdx.x * 64, c0 = blockIdx.y * 64;
    const float* ip = in + (size_t)blockIdx.z * R * C;
    unsigned short* op = out + (size_t)blockIdx.z * (size_t)R * C;

    int rl = t >> 4, c4 = (t & 15) * 4;
#pragma unroll
    for (int p = 0; p < 4; p++) {
        int r = p * 16 + rl;
        float4 v = *(const float4*)(ip + (size_t)(r0 + r) * C + c0 + c4);
        Ls[(c4 + 0) * 72 + r] = f2b(v.x);
        Ls[(c4 + 1) * 72 + r] = f2b(v.y);
        Ls[(c4 + 2) * 72 + r] = f2b(v.z);
        Ls[(c4 + 3) * 72 + r] = f2b(v.w);
    }
    __syncthreads();
    int c = t >> 2, j2 = (t & 3) * 2;
    int orow = c0 + c;
    int blk = orow >> 7, rl2 = orow & 127;
#pragma unroll
    for (int q = 0; q < 2; q++) {
        int j = j2 + q;
        int kk = r0 + j * 8;   // output col
        uint4 v = *(const uint4*)&Ls[c * 72 + j * 8];
        size_t dst = (size_t)blk * 128 * R + (size_t)(kk >> 5) * 4096 + rl2 * 32 + (kk & 31);
        *(uint4*)(op + dst) = v;
    }
}

// ---------------- gating: one wave per token ----------------
__global__ __launch_bounds__(256) void gate_kernel(
    const float* __restrict__ x, const float* __restrict__ Wg,
    const float* __restrict__ bg, int* __restrict__ cnt,
    int* __restrict__ btok, float* __restrict__ bw,
    int* __restrict__ tokSlot, int T)
{
    int wave = threadIdx.x >> 6;
    int lane = threadIdx.x & 63;
    int t = blockIdx.x * 4 + wave;
    if (t >= T) return;

    float part[NE];
#pragma unroll
    for (int e = 0; e < NE; e++) part[e] = 0.f;
    const float* xr = x + (size_t)t * HD;
#pragma unroll 4
    for (int j = 0; j < 16; j++) {
        int h = lane + 64 * j;
        float xv = xr[h];
        const float* wr = Wg + h * NE;
#pragma unroll
        for (int e = 0; e < NE; e++) part[e] += xv * wr[e];
    }
#pragma unroll
    for (int e = 0; e < NE; e++) {
        float v = part[e];
        for (int off = 32; off >= 1; off >>= 1) v += __shfl_xor(v, off, 64);
        part[e] = v;
    }
    if (lane == 0) {
        float lg[NE];
#pragma unroll
        for (int e = 0; e < NE; e++) lg[e] = part[e] + bg[e];
        int i0 = 0;
        for (int e = 1; e < NE; e++) if (lg[e] > lg[i0]) i0 = e;
        int i1 = -1;
        for (int e = 0; e < NE; e++) {
            if (e == i0) continue;
            if (i1 < 0 || lg[e] > lg[i1]) i1 = e;
        }
        float e1 = expf(lg[i1] - lg[i0]);
        float s = 1.0f + e1;
        float w0 = 1.0f / s, w1 = e1 / s;
        int p0 = atomicAdd(&cnt[i0], 1);
        int p1 = atomicAdd(&cnt[i1], 1);
        btok[i0 * CAP + p0] = t; bw[i0 * CAP + p0] = w0;
        btok[i1 * CAP + p1] = t; bw[i1 * CAP + p1] = w1;
        tokSlot[t * 2 + 0] = i0 * CAP + p0;
        tokSlot[t * 2 + 1] = i1 * CAP + p1;
    }
}

__global__ void scan_kernel(const int* __restrict__ cnt, int* __restrict__ offs)
{
    if (threadIdx.x == 0) {
        int acc = 0;
        for (int e = 0; e < NE; e++) { offs[e] = acc; acc += cnt[e]; }
    }
}

// ---------------- GEMM1: h = silu(x@W1) * (x@W3) ----------------
// 128x128 tile, BK=32, 3-deep counted-vmcnt pipeline.
// LDS row-major [128][32] bf16: b128 frag reads (row*64B + quad*16B) hit 8 even
// bank-starts x 8 lanes = conflict-free, no swizzle.
// Staging all-gll16: B from packed weights (1KB contiguous per gll16);
// A gather 4-lanes-per-row (16x64B transactions per gll16).
__global__ __launch_bounds__(256, 2) void gemm1_kernel(
    const unsigned short* __restrict__ xbf, const unsigned short* __restrict__ Wt1,
    const unsigned short* __restrict__ Wt3, const int* __restrict__ btok,
    const int* __restrict__ cnt, const int* __restrict__ offs,
    unsigned short* __restrict__ h_buf)
{
    int e = blockIdx.z;
    int ne = cnt[e];
    int m0 = blockIdx.y * 128;
    if (m0 >= ne) return;
    int f0 = blockIdx.x * 128;

    __shared__ unsigned short As[3][4096];
    __shared__ unsigned short B1s[3][4096];
    __shared__ unsigned short B3s[3][4096];

    int tid = threadIdx.x;
    int lane = tid & 63;
    int w = tid >> 6;
    int wm = (w >> 1) * 64, wn = (w & 1) * 64;
    int l15 = lane & 15, quad = lane >> 4;

    // packed-weight bases for this f-block
    const unsigned short* W1e = Wt1 + (size_t)e * HD * FD + (size_t)blockIdx.x * (128 * HD);
    const unsigned short* W3e = Wt3 + (size_t)e * HD * FD + (size_t)blockIdx.x * (128 * HD);

    // staging: wave w owns row-groups g = 2w, 2w+1 (16 rows each)
    const unsigned short* aA[2];
    const unsigned short* aB1[2];
    const unsigned short* aB3[2];
    int dst[2];
#pragma unroll
    for (int q = 0; q < 2; q++) {
        int g = w * 2 + q;                   // 0..7
        int row = g * 16 + (lane >> 2);      // per-lane row, 4 lanes/row
        int cofs = (lane & 3) * 8;           // 4 x 16B chunks per 64B row-slice
        dst[q] = g * 512;                    // shorts; lane l lands at +l*8 (row-major [128][32])
        int ridx = m0 + row; if (ridx >= ne) ridx = ne - 1;
        int tok = btok[e * CAP + ridx];
        aA[q]  = xbf + (size_t)tok * HD + cofs;        // advance +32 shorts per K-step
        aB1[q] = W1e + g * 512 + lane * 8;             // packed: advance +4096 per K-step
        aB3[q] = W3e + g * 512 + lane * 8;
    }

    // fragment read offsets (shorts), row-major: row*32 + quad*8
    int aoff[4], boff[4];
#pragma unroll
    for (int i = 0; i < 4; i++) {
        aoff[i] = (wm + i * 16 + l15) * 32 + quad * 8;
        boff[i] = (wn + i * 16 + l15) * 32 + quad * 8;
    }

    f32x4 accG[4][4], accU[4][4];
    f32x4 z = {0.f, 0.f, 0.f, 0.f};
#pragma unroll
    for (int i = 0; i < 4; i++)
#pragma unroll
        for (int jj = 0; jj < 4; jj++) { accG[i][jj] = z; accU[i][jj] = z; }

    // prologue: stage k=0 -> buf0, k=1 -> buf1
#pragma unroll
    for (int q = 0; q < 2; q++) {
        gll16(aA[q],  &As[0][dst[q]]);
        gll16(aB1[q], &B1s[0][dst[q]]);
        gll16(aB3[q], &B3s[0][dst[q]]);
    }
#pragma unroll
    for (int q = 0; q < 2; q++) {
        gll16(aA[q]  + 32,   &As[1][dst[q]]);
        gll16(aB1[q] + 4096, &B1s[1][dst[q]]);
        gll16(aB3[q] + 4096, &B3s[1][dst[q]]);
    }

    const int NK = HD / 32;   // 32
    int cur = 0;
    for (int k = 0; k < NK; ++k) {
        if (k + 2 < NK) {
            int nb = cur + 2; if (nb >= 3) nb -= 3;
#pragma unroll
            for (int q = 0; q < 2; q++) {
                gll16(aA[q]  + (k + 2) * 32,            &As[nb][dst[q]]);
                gll16(aB1[q] + (size_t)(k + 2) * 4096,  &B1s[nb][dst[q]]);
                gll16(aB3[q] + (size_t)(k + 2) * 4096,  &B3s[nb][dst[q]]);
            }
            asm volatile("s_waitcnt vmcnt(12)\ns_barrier" ::: "memory");
        } else if (k + 1 < NK) {
            asm volatile("s_waitcnt vmcnt(6)\ns_barrier" ::: "memory");
        } else {
            asm volatile("s_waitcnt vmcnt(0)\ns_barrier" ::: "memory");
        }

        __builtin_amdgcn_s_setprio(1);
        short8 af[4], b1f[4], b3f[4];
#pragma unroll
        for (int mt = 0; mt < 4; mt++) af[mt] = *(const short8*)&As[cur][aoff[mt]];
#pragma unroll
        for (int nt = 0; nt < 4; nt++) {
            b1f[nt] = *(const short8*)&B1s[cur][boff[nt]];
            b3f[nt] = *(const short8*)&B3s[cur][boff[nt]];
        }
#pragma unroll
        for (int mt = 0; mt < 4; mt++)
#pragma unroll
            for (int nt = 0; nt < 4; nt++) {
                accG[mt][nt] = __builtin_amdgcn_mfma_f32_16x16x32_bf16(af[mt], b1f[nt], accG[mt][nt], 0, 0, 0);
                accU[mt][nt] = __builtin_amdgcn_mfma_f32_16x16x32_bf16(af[mt], b3f[nt], accU[mt][nt], 0, 0, 0);
            }
        __builtin_amdgcn_s_setprio(0);
        asm volatile("s_barrier" ::: "memory");
        cur++; if (cur >= 3) cur -= 3;
    }

    // epilogue: silu(g)*u -> bf16 -> h_buf (linear layout)
    int base = offs[e] + m0;
#pragma unroll
    for (int mt = 0; mt < 4; mt++) {
#pragma unroll
        for (int r = 0; r < 4; r++) {
            int rowl = wm + mt * 16 + quad * 4 + r;
            if (m0 + rowl < ne) {
                size_t rb = (size_t)(base + rowl) * FD;
#pragma unroll
                for (int nt = 0; nt < 4; nt++) {
                    int f = f0 + wn + nt * 16 + l15;
                    float g = accG[mt][nt][r];
                    float u = accU[mt][nt][r];
                    float h = g / (1.f + expf(-g)) * u;
                    h_buf[rb + f] = f2b(h);
                }
            }
        }
    }
}

// ---------------- GEMM2: contrib = cw * (h @ W2) ----------------
// Same structure; A rows from h_buf are contiguous -> 4-lanes-per-row gather;
// B from packed Wt2 -> contiguous 1KB per gll16. vmcnt(8)/4/0, 3 blocks/CU.
__global__ __launch_bounds__(256, 3) void gemm2_kernel(
    const unsigned short* __restrict__ h_buf, const unsigned short* __restrict__ Wt2,
    const float* __restrict__ bw, const int* __restrict__ cnt,
    const int* __restrict__ offs, float* __restrict__ contrib)
{
    int e = blockIdx.z;
    int ne = cnt[e];
    int m0 = blockIdx.y * 128;
    if (m0 >= ne) return;
    int h0 = blockIdx.x * 128;

    __shared__ unsigned short As[3][4096];
    __shared__ unsigned short Bs[3][4096];

    int tid = threadIdx.x;
    int lane = tid & 63;
    int w = tid >> 6;
    int wm = (w >> 1) * 64, wn = (w & 1) * 64;
    int l15 = lane & 15, quad = lane >> 4;
    int obase = offs[e];

    const unsigned short* W2e = Wt2 + (size_t)e * FD * HD + (size_t)blockIdx.x * (128 * FD);

    const unsigned short* aA[2];
    const unsigned short* aB[2];
    int dst[2];
#pragma unroll
    for (int q = 0; q < 2; q++) {
        int g = w * 2 + q;
        int row = g * 16 + (lane >> 2);
        int cofs = (lane & 3) * 8;
        dst[q] = g * 512;
        int ridx = m0 + row; if (ridx >= ne) ridx = ne - 1;
        aA[q] = h_buf + (size_t)(obase + ridx) * FD + cofs;   // +32 per K-step
        aB[q] = W2e + g * 512 + lane * 8;                     // +4096 per K-step
    }

    int aoff[4], boff[4];
#pragma unroll
    for (int i = 0; i < 4; i++) {
        aoff[i] = (wm + i * 16 + l15) * 32 + quad * 8;
        boff[i] = (wn + i * 16 + l15) * 32 + quad * 8;
    }

    f32x4 acc[4][4];
    f32x4 z = {0.f, 0.f, 0.f, 0.f};
#pragma unroll
    for (int i = 0; i < 4; i++)
#pragma unroll
        for (int jj = 0; jj < 4; jj++) acc[i][jj] = z;

#pragma unroll
    for (int q = 0; q < 2; q++) {
        gll16(aA[q], &As[0][dst[q]]);
        gll16(aB[q], &Bs[0][dst[q]]);
    }
#pragma unroll
    for (int q = 0; q < 2; q++) {
        gll16(aA[q] + 32,   &As[1][dst[q]]);
        gll16(aB[q] + 4096, &Bs[1][dst[q]]);
    }

    const int NK = FD / 32;   // 128
    int cur = 0;
    for (int k = 0; k < NK; ++k) {
        if (k + 2 < NK) {
            int nb = cur + 2; if (nb >= 3) nb -= 3;
#pragma unroll
            for (int q = 0; q < 2; q++) {
                gll16(aA[q] + (k + 2) * 32,           &As[nb][dst[q]]);
                gll16(aB[q] + (size_t)(k + 2) * 4096, &Bs[nb][dst[q]]);
            }
            asm volatile("s_waitcnt vmcnt(8)\ns_barrier" ::: "memory");
        } else if (k + 1 < NK) {
            asm volatile("s_waitcnt vmcnt(4)\ns_barrier" ::: "memory");
        } else {
            asm volatile("s_waitcnt vmcnt(0)\ns_barrier" ::: "memory");
        }

        __builtin_amdgcn_s_setprio(1);
        short8 af[4], bf[4];
#pragma unroll
        for (int mt = 0; mt < 4; mt++) af[mt] = *(const short8*)&As[cur][aoff[mt]];
#pragma unroll
        for (int nt = 0; nt < 4; nt++) bf[nt] = *(const short8*)&Bs[cur][boff[nt]];
#pragma unroll
        for (int mt = 0; mt < 4; mt++)
#pragma unroll
            for (int nt = 0; nt < 4; nt++)
                acc[mt][nt] = __builtin_amdgcn_mfma_f32_16x16x32_bf16(af[mt], bf[nt], acc[mt][nt], 0, 0, 0);
        __builtin_amdgcn_s_setprio(0);
        asm volatile("s_barrier" ::: "memory");
        cur++; if (cur >= 3) cur -= 3;
    }

    int base = obase + m0;
#pragma unroll
    for (int mt = 0; mt < 4; mt++) {
#pragma unroll
        for (int r = 0; r < 4; r++) {
            int rowl = wm + mt * 16 + quad * 4 + r;
            if (m0 + rowl < ne) {
                float wgt = bw[e * CAP + m0 + rowl];
                size_t rb = (size_t)(base + rowl) * HD;
#pragma unroll
                for (int nt = 0; nt < 4; nt++) {
                    int col = h0 + wn + nt * 16 + l15;
                    contrib[rb + col] = acc[mt][nt][r] * wgt;
                }
            }
        }
    }
}

// ---------------- combine ----------------
__global__ __launch_bounds__(256) void combine_kernel(
    const float* __restrict__ contrib, const int* __restrict__ tokSlot,
    const int* __restrict__ offs, float* __restrict__ out)
{
    int t = blockIdx.x;
    int i = threadIdx.x;
    int s0 = tokSlot[t * 2 + 0];
    int s1 = tokSlot[t * 2 + 1];
    int r0 = offs[s0 >> 12] + (s0 & (CAP - 1));
    int r1 = offs[s1 >> 12] + (s1 & (CAP - 1));
    float4 a = *(const float4*)(contrib + (size_t)r0 * HD + i * 4);
    float4 b = *(const float4*)(contrib + (size_t)r1 * HD + i * 4);
    float4 o;
    o.x = a.x + b.x; o.y = a.y + b.y; o.z = a.z + b.z; o.w = a.w + b.w;
    *(float4*)(out + (size_t)t * HD + i * 4) = o;
}

extern "C" void kernel_launch(void* const* d_in, const int* in_sizes, int n_in,
                              void* d_out, int out_size, void* d_ws, size_t ws_size,
                              hipStream_t stream)
{
    const float* x  = (const float*)d_in[0];
    const float* Wg = (const float*)d_in[1];
    const float* bg = (const float*)d_in[2];
    const float* W1 = (const float*)d_in[3];
    const float* W3 = (const float*)d_in[4];
    const float* W2 = (const float*)d_in[5];
    float* out = (float*)d_out;
    int T = in_sizes[0] / HD;   // 4096 tokens

    // ws layout (~304 MB)
    char* ws = (char*)d_ws;
    int*   cnt     = (int*)ws;
    int*   offs    = cnt + 8;
    int*   btok    = (int*)(ws + 1024);
    float* bw      = (float*)(ws + 1024 + 131072);
    int*   tokSlot = (int*)(ws + 1024 + 262144);
    unsigned short* xbf = (unsigned short*)(ws + ((size_t)1 << 20));                 // 8 MB
    unsigned short* Wt1 = (unsigned short*)(ws + ((size_t)16 << 20));                // 64 MB
    unsigned short* Wt3 = (unsigned short*)(ws + ((size_t)80 << 20));                // 64 MB
    unsigned short* Wt2 = (unsigned short*)(ws + ((size_t)144 << 20));               // 64 MB
    unsigned short* h_buf = (unsigned short*)(ws + ((size_t)208 << 20));             // 64 MB
    float* contrib = (float*)(ws + ((size_t)272 << 20));                             // 32 MB

    hipMemsetAsync(cnt, 0, 8 * sizeof(int), stream);

    convx_kernel<<<(T * HD) / 1024, 256, 0, stream>>>(x, xbf);
    dim3 tg1(HD / 64, FD / 64, NE);
    transpose_kernel<<<tg1, 256, 0, stream>>>(W1, Wt1, HD, FD);
    transpose_kernel<<<tg1, 256, 0, stream>>>(W3, Wt3, HD, FD);
    dim3 tg2(FD / 64, HD / 64, NE);
    transpose_kernel<<<tg2, 256, 0, stream>>>(W2, Wt2, FD, HD);

    gate_kernel<<<(T + 3) / 4, 256, 0, stream>>>(x, Wg, bg, cnt, btok, bw, tokSlot, T);
    scan_kernel<<<1, 64, 0, stream>>>(cnt, offs);

    dim3 g1(FD / 128, CAP / 128, NE);
    gemm1_kernel<<<g1, 256, 0, stream>>>(xbf, Wt1, Wt3, btok, cnt, offs, h_buf);

    dim3 g2(HD / 128, CAP / 128, NE);
    gemm2_kernel<<<g2, 256, 0, stream>>>(h_buf, Wt2, bw, cnt, offs, contrib);

    combine_kernel<<<T, 256, 0, stream>>>(contrib, tokSlot, offs, out);
}